// Round 4
// baseline (107.105 us; speedup 1.0000x reference)
//
#include <hip/hip_runtime.h>
#include <hip/hip_bf16.h>

typedef short bf16x8 __attribute__((ext_vector_type(8)));
typedef short bf16x4 __attribute__((ext_vector_type(4)));
typedef float f32x4  __attribute__((ext_vector_type(4)));

#define NI 256
#define NJ 256
#define NC 128
#define NH 4
#define ND 32

// ---- workspace layout (bytes) ----
#define WB_OFF    0           // wqkv bf16 [384][128]  (row = op*128 + h*32 + d)
#define WO_BF_OFF 98304       // wo bf16 [128][128]
#define XN_OFF    131072      // xn bf16 [65536 tok][128]
#define TBM_OFF   16908288    // [1024 ih][256] f32 (tb + mask bias)
#define OG_OFF    17956864    // O bf16 [4 h][65536 tok][32]
// end = 34,734,080 bytes

__device__ __forceinline__ short f2bf(float f) {
    return __builtin_bit_cast(short, __float2bfloat16(f));
}

typedef __attribute__((address_space(1))) const void gvoid_t;
typedef __attribute__((address_space(3))) void svoid_t;
__device__ __forceinline__ void load_lds16(const void* g, void* l) {
    __builtin_amdgcn_global_load_lds((gvoid_t*)g, (svoid_t*)l, 16, 0, 0);
}

// ================= k_conv: weights f32 -> bf16 (once) =================
__global__ __launch_bounds__(256, 8)
void k_conv(const float* __restrict__ wq, const float* __restrict__ wk,
            const float* __restrict__ wv, const float* __restrict__ wo,
            char* __restrict__ ws)
{
    const int gt = blockIdx.x * 256 + threadIdx.x;   // grid 64
    const int base = gt * 4;                          // 65536 elems total
    const float* src;
    short* dst;
    if (base < 49152) {
        const int t = base >> 14;                     // 0=q 1=k 2=v
        src = (t == 0 ? wq : (t == 1 ? wk : wv)) + (base & 16383);
        dst = (short*)(ws + WB_OFF) + base;
    } else {
        src = wo + (base - 49152);
        dst = (short*)(ws + WO_BF_OFF) + (base - 49152);
    }
    f32x4 v = *(const f32x4*)src;
    bf16x4 o;
    #pragma unroll
    for (int r = 0; r < 4; ++r) o[r] = f2bf(v[r]);
    *(bf16x4*)dst = o;
}

// ================= k_ln: LayerNorm + tb + mask bias =================
__global__ __launch_bounds__(512, 4)
void k_ln(const float* __restrict__ x, const float* __restrict__ mask,
          const float* __restrict__ ln_g, const float* __restrict__ ln_b,
          const float* __restrict__ wb, char* __restrict__ ws)
{
    const int tid = threadIdx.x;
    const int t   = tid >> 2;           // 0..127
    const int p   = tid & 3;
    const int ch  = p * 32;
    const size_t tok = (size_t)blockIdx.x * 128 + t;   // grid 512

    const float* xr = x + tok * NC + ch;
    f32x4 vx[8];
    float s0 = 0.f;
    #pragma unroll
    for (int u = 0; u < 8; ++u) {
        vx[u] = *(const f32x4*)(xr + 4 * u);
        s0 += vx[u][0] + vx[u][1] + vx[u][2] + vx[u][3];
    }
    s0 += __shfl_xor(s0, 1);
    s0 += __shfl_xor(s0, 2);
    const float mu = s0 * 0.0078125f;
    float v0 = 0.f;
    #pragma unroll
    for (int u = 0; u < 8; ++u) {
        #pragma unroll
        for (int e = 0; e < 4; ++e) { float d = vx[u][e] - mu; v0 += d * d; }
    }
    v0 += __shfl_xor(v0, 1);
    v0 += __shfl_xor(v0, 2);
    const float rs = rsqrtf(v0 * 0.0078125f + 1e-5f);
    #pragma unroll
    for (int u = 0; u < 8; ++u) {
        f32x4 gg = *(const f32x4*)(ln_g + ch + 4 * u);
        f32x4 bb = *(const f32x4*)(ln_b + ch + 4 * u);
        #pragma unroll
        for (int e = 0; e < 4; ++e) vx[u][e] = (vx[u][e] - mu) * rs * gg[e] + bb[e];
    }

    // tb (f32 xn, per-query; cancels in softmax but matched to reference numerics)
    float tb[4];
    #pragma unroll
    for (int h = 0; h < 4; ++h) {
        const float* wr = wb + h * NC + ch;
        float a = 0.f;
        #pragma unroll
        for (int u = 0; u < 8; ++u) {
            f32x4 w4 = *(const f32x4*)(wr + 4 * u);
            #pragma unroll
            for (int e = 0; e < 4; ++e) a += vx[u][e] * w4[e];
        }
        a += __shfl_xor(a, 1);
        a += __shfl_xor(a, 2);
        tb[h] = a;
    }
    if (p == 0) {
        const float mb = 1.0e9f * (mask[tok] - 1.0f);
        const size_t i = tok >> 8, j = tok & 255;
        float* tbm = (float*)(ws + TBM_OFF);
        #pragma unroll
        for (int h = 0; h < 4; ++h)
            tbm[(i * NH + h) * NJ + j] = tb[h] + mb;
    }

    short* xnrow = (short*)(ws + XN_OFF) + tok * NC + ch;
    #pragma unroll
    for (int cc = 0; cc < 4; ++cc) {
        bf16x8 o8;
        #pragma unroll
        for (int e = 0; e < 4; ++e) {
            o8[e]     = f2bf(vx[2 * cc][e]);
            o8[4 + e] = f2bf(vx[2 * cc + 1][e]);
        }
        *(bf16x8*)(xnrow + 8 * cc) = o8;
    }
}

// ================= k_fat: fused QKV projection + attention per (i,h) =================
__global__ __launch_bounds__(512, 4)   // <=128 VGPR, 2 blocks/CU (LDS 68KB)
void k_fat(char* __restrict__ ws)
{
    __shared__ short kls[256][40];        // 20,480 B  k[tok][d]
    __shared__ short vls[32][264];        // 16,896 B  vT[d][tok]
    __shared__ short pbuf[8][3][16][40];  // 30,720 B  per-wave: slots 0,1 = q tiles; 2 = scratch

    const int tid  = threadIdx.x;
    const int lane = tid & 63;
    const int wid  = tid >> 6;
    const int g    = lane >> 4;
    const int l16  = lane & 15;
    const int ih   = blockIdx.x;          // grid 1024
    const int i    = ih >> 2;
    const int h    = ih & 3;

    const short* xn   = (const short*)(ws + XN_OFF) + (size_t)i * NJ * NC;
    const short* wqkv = (const short*)(ws + WB_OFF);
    const float* tbm  = (const float*)(ws + TBM_OFF) + (size_t)ih * NJ;
    short* og = (short*)(ws + OG_OFF) + ((size_t)h * (NI * NJ) + (size_t)i * NJ) * ND;

    const f32x4 z4 = {0.f, 0.f, 0.f, 0.f};

    // ---- Phase A: each wave projects q,k,v for its own 32 tokens ----
    #pragma unroll
    for (int tile = 0; tile < 2; ++tile) {
        const int tq = wid * 32 + tile * 16;
        bf16x8 af[4];
        #pragma unroll
        for (int ks = 0; ks < 4; ++ks)
            af[ks] = *(const bf16x8*)(xn + (size_t)(tq + l16) * NC + ks * 32 + g * 8);
        #pragma unroll
        for (int op = 0; op < 3; ++op) {
            #pragma unroll
            for (int sub = 0; sub < 2; ++sub) {
                const short* wrow = wqkv + (size_t)(op * 128 + h * 32 + sub * 16 + l16) * NC + g * 8;
                f32x4 acc = z4;
                #pragma unroll
                for (int ks = 0; ks < 4; ++ks) {
                    bf16x8 bf = *(const bf16x8*)(wrow + ks * 32);
                    acc = __builtin_amdgcn_mfma_f32_16x16x32_bf16(af[ks], bf, acc, 0, 0, 0);
                }
                if (op == 0) {
                    #pragma unroll
                    for (int r = 0; r < 4; ++r)
                        pbuf[wid][tile][g * 4 + r][sub * 16 + l16] = f2bf(acc[r]);
                } else if (op == 1) {
                    #pragma unroll
                    for (int r = 0; r < 4; ++r)
                        kls[tq + g * 4 + r][sub * 16 + l16] = f2bf(acc[r]);
                } else {
                    bf16x4 pk;
                    #pragma unroll
                    for (int r = 0; r < 4; ++r) pk[r] = f2bf(acc[r]);
                    *(bf16x4*)(&vls[sub * 16 + l16][tq + g * 4]) = pk;
                }
            }
        }
    }
    __syncthreads();   // the only barrier

    const float SCALE = 0.17677669529663687f;  // 1/sqrt(32)

    // ---- Phase B: attention (proven round-1/3 code path) ----
    #pragma unroll
    for (int qt = 0; qt < 2; ++qt) {
        const int tq = wid * 32 + qt * 16;
        f32x4 tbmb = *(const f32x4*)(tbm + tq + g * 4);

        bf16x8 qf = *(const bf16x8*)(&pbuf[wid][qt][l16][g * 8]);
        f32x4 s[16];
        #pragma unroll
        for (int kt = 0; kt < 16; ++kt) {
            bf16x8 kf = *(const bf16x8*)(&kls[kt * 16 + l16][g * 8]);
            s[kt] = __builtin_amdgcn_mfma_f32_16x16x32_bf16(qf, kf, z4, 0, 0, 0);
        }
        #pragma unroll
        for (int kt = 0; kt < 16; ++kt)
            #pragma unroll
            for (int r = 0; r < 4; ++r)
                s[kt][r] = fmaf(s[kt][r], SCALE, tbmb[r]);  // fp32: masked rows collapse exactly

        f32x4 mx = s[0];
        #pragma unroll
        for (int kt = 1; kt < 16; ++kt)
            #pragma unroll
            for (int r = 0; r < 4; ++r) mx[r] = fmaxf(mx[r], s[kt][r]);
        #pragma unroll
        for (int d = 1; d < 16; d <<= 1)
            #pragma unroll
            for (int r = 0; r < 4; ++r) mx[r] = fmaxf(mx[r], __shfl_xor(mx[r], d));

        f32x4 sum = z4;
        #pragma unroll
        for (int kt = 0; kt < 16; ++kt)
            #pragma unroll
            for (int r = 0; r < 4; ++r) { s[kt][r] = __expf(s[kt][r] - mx[r]); sum[r] += s[kt][r]; }
        #pragma unroll
        for (int d = 1; d < 16; d <<= 1)
            #pragma unroll
            for (int r = 0; r < 4; ++r) sum[r] += __shfl_xor(sum[r], d);
        f32x4 inv;
        #pragma unroll
        for (int r = 0; r < 4; ++r) inv[r] = 1.0f / sum[r];
        #pragma unroll
        for (int kt = 0; kt < 16; ++kt)
            #pragma unroll
            for (int r = 0; r < 4; ++r) s[kt][r] *= inv[r];

        // PV: per-wave staging, slots alternate {2,0} (q0 consumed; q1 in slot 1 preserved)
        f32x4 oacc0 = z4, oacc1 = z4;
        #pragma unroll
        for (int c = 0; c < 8; ++c) {
            short* pb = &pbuf[wid][(c & 1) ? 0 : 2][0][0];
            #pragma unroll
            for (int kk = 0; kk < 2; ++kk) {
                #pragma unroll
                for (int r = 0; r < 4; ++r)
                    pb[(g * 4 + r) * 40 + kk * 16 + l16] = f2bf(s[c * 2 + kk][r]);
            }
            bf16x8 a   = *(const bf16x8*)(pb + l16 * 40 + g * 8);
            bf16x8 vb0 = *(const bf16x8*)(&vls[l16][c * 32 + g * 8]);
            bf16x8 vb1 = *(const bf16x8*)(&vls[16 + l16][c * 32 + g * 8]);
            oacc0 = __builtin_amdgcn_mfma_f32_16x16x32_bf16(a, vb0, oacc0, 0, 0, 0);
            oacc1 = __builtin_amdgcn_mfma_f32_16x16x32_bf16(a, vb1, oacc1, 0, 0, 0);
        }

        // O store: og[h][i*256 + tok][32] — contiguous 32B segments
        #pragma unroll
        for (int r = 0; r < 4; ++r) {
            const int tok = tq + g * 4 + r;
            og[(size_t)tok * ND + l16]      = f2bf(oacc0[r]);
            og[(size_t)tok * ND + 16 + l16] = f2bf(oacc1[r]);
        }
    }
}

// ================= k_oproj: out = O @ wo^T + bias =================
__global__ __launch_bounds__(512, 4)
void k_oproj(const char* __restrict__ ws, const float* __restrict__ wo_b,
             float* __restrict__ out)
{
    __shared__ short ol[4][128][32];   // 32,768 B, linear per h-chunk

    const int tid  = threadIdx.x;
    const int lane = tid & 63;
    const int wid  = tid >> 6;
    const int g    = lane >> 4;
    const int l16  = lane & 15;
    const size_t tok0 = (size_t)blockIdx.x * 128;   // grid 512

    const short* ogb = (const short*)(ws + OG_OFF);
    for (int c = wid; c < 32; c += 8) {
        const int hh = c >> 3, cc = c & 7;
        const char* src = (const char*)(ogb + ((size_t)hh * (NI * NJ) + tok0) * ND) + cc * 1024 + lane * 16;
        load_lds16(src, (char*)ol + c * 1024);
    }
    __syncthreads();

    const short* wrow = (const short*)(ws + WO_BF_OFF) + (size_t)(wid * 16 + l16) * NC + g * 8;
    bf16x8 bfr[4];
    #pragma unroll
    for (int ks = 0; ks < 4; ++ks) bfr[ks] = *(const bf16x8*)(wrow + ks * 32);

    const float bias = wo_b[wid * 16 + l16];
    const f32x4 z4 = {0.f, 0.f, 0.f, 0.f};

    #pragma unroll
    for (int mt = 0; mt < 8; ++mt) {
        f32x4 acc = z4;
        #pragma unroll
        for (int ks = 0; ks < 4; ++ks) {
            // O feature index = ks*32 + g*8 + e  (h-chunk ks, dim g*8+e)
            bf16x8 av = *(const bf16x8*)(&ol[ks][mt * 16 + l16][g * 8]);
            acc = __builtin_amdgcn_mfma_f32_16x16x32_bf16(av, bfr[ks], acc, 0, 0, 0);
        }
        #pragma unroll
        for (int r = 0; r < 4; ++r)
            out[(tok0 + mt * 16 + g * 4 + r) * NC + wid * 16 + l16] = acc[r] + bias;
    }
}

extern "C" void kernel_launch(void* const* d_in, const int* in_sizes, int n_in,
                              void* d_out, int out_size, void* d_ws, size_t ws_size,
                              hipStream_t stream) {
    const float* x    = (const float*)d_in[0];
    const float* mask = (const float*)d_in[1];
    const float* ln_g = (const float*)d_in[2];
    const float* ln_b = (const float*)d_in[3];
    const float* wq   = (const float*)d_in[4];
    const float* wk   = (const float*)d_in[5];
    const float* wv   = (const float*)d_in[6];
    const float* wb   = (const float*)d_in[7];
    const float* wo   = (const float*)d_in[8];
    const float* wo_b = (const float*)d_in[9];
    float* out = (float*)d_out;
    char* ws   = (char*)d_ws;

    k_conv <<<dim3(64),     dim3(256), 0, stream>>>(wq, wk, wv, wo, ws);
    k_ln   <<<dim3(512),    dim3(512), 0, stream>>>(x, mask, ln_g, ln_b, wb, ws);
    k_fat  <<<dim3(NI * NH), dim3(512), 0, stream>>>(ws);
    k_oproj<<<dim3(512),    dim3(512), 0, stream>>>(ws, wo_b, out);
}